// Round 8
// baseline (4268.489 us; speedup 1.0000x reference)
//
#include <hip/hip_runtime.h>
#include <hip/hip_bf16.h>

#define VOCAB 50000
#define EMB   300
#define HID   1024
#define TT    512
#define BB    64

// Block layout for pre: [t][kb=64][row=64][c=16] bf16; per-t slab = 65536 shorts.
// h1/h2 are 2-slab rings (slab = t&1); the per-step all-to-all flag barrier
// guarantees ring-2 reuse safety.
//
// Pipelined scan, proj FUSED INTO LAYER 0: 128 WGs.
//   WGs 0..63  (L=0): pre0[t] computed IN-STEP from a prefetched emb gather
//     (10 MFMAs vs LDS-resident 16x300 Wih0 slice; A-fragments prefetched one
//     step ahead, xidx two ahead -> gather latency hidden under the step).
//     h1[t] = tanh(pre0 + h1[t-1]Whh0^T + bih0 + bhh0). FUSE: pre1[t-1] =
//     h1[t-1]*Wih1^T + bih1 via LDS tile -> full-line sc1 stores, drained
//     before flagA[bx] = t+1.
//   WGs 64..127 (L=1): h2[t] = tanh(pre1[t] + h2[t-1]Whh1^T + bhh1), step t
//     gated on flagsA[bx] >= t+2. A never waits on B -> no deadlock.
//
// NOTE on asm loads: asm "=v" load results must NEVER be live across a
// variable-trip loop and keep short straight-line ranges (allocator may spill
// them before the data lands). The A-gather prefetch uses COMPILER loads
// (dataflow-aware, safe across the spin); they are issued BEFORE the asm
// h-loads, hence older in the vmcnt queue -> WAIT_VM16(N) semantics only get
// stricter, never weaker.

typedef __attribute__((ext_vector_type(8))) short short8;
typedef __attribute__((ext_vector_type(4))) float floatx4;

__device__ inline float b2f(unsigned int u) {
    union { unsigned int i; float f; } v; v.i = u << 16; return v.f;
}
__device__ inline unsigned short f2b(float f) {
    __hip_bfloat16 h = __float2bfloat16(f);
    return *reinterpret_cast<unsigned short*>(&h);
}

#define WAIT_VM16(N, A) asm volatile("s_waitcnt vmcnt(" #N ")"              \
    : "+v"((A)[0]), "+v"((A)[1]), "+v"((A)[2]), "+v"((A)[3]),               \
      "+v"((A)[4]), "+v"((A)[5]), "+v"((A)[6]), "+v"((A)[7]),               \
      "+v"((A)[8]), "+v"((A)[9]), "+v"((A)[10]), "+v"((A)[11]),             \
      "+v"((A)[12]), "+v"((A)[13]), "+v"((A)[14]), "+v"((A)[15])            \
    :: "memory")

// A-fragment gather for one emb row (row picked by xq), k = kk*32 + quad*8.
// Tail (kk=9, k=288..319): quad0 full, quad1 first 4 real, quad2/3 zero;
// all loads 8B/16B aligned (600B bf16 rows are 8B-aligned, 1200B fp32 rows
// 16B-aligned, k multiples of 8).
__device__ __forceinline__ void prefetch_A(const void* emb, int mode, int xq,
                                           int quad, short8* af)
{
    if (mode) {
        const float* Af = (const float*)emb + (size_t)xq * EMB;
        #pragma unroll
        for (int kk = 0; kk < 9; ++kk) {
            int k = kk * 32 + quad * 8;
            float4 f0 = *(const float4*)(Af + k);
            float4 f1 = *(const float4*)(Af + k + 4);
            short8 a;
            a[0]=f2b(f0.x); a[1]=f2b(f0.y); a[2]=f2b(f0.z); a[3]=f2b(f0.w);
            a[4]=f2b(f1.x); a[5]=f2b(f1.y); a[6]=f2b(f1.z); a[7]=f2b(f1.w);
            af[kk] = a;
        }
        short8 a = {0,0,0,0,0,0,0,0};
        if (quad == 0) {
            float4 f0 = *(const float4*)(Af + 288);
            float4 f1 = *(const float4*)(Af + 292);
            a[0]=f2b(f0.x); a[1]=f2b(f0.y); a[2]=f2b(f0.z); a[3]=f2b(f0.w);
            a[4]=f2b(f1.x); a[5]=f2b(f1.y); a[6]=f2b(f1.z); a[7]=f2b(f1.w);
        } else if (quad == 1) {
            float4 f0 = *(const float4*)(Af + 296);
            a[0]=f2b(f0.x); a[1]=f2b(f0.y); a[2]=f2b(f0.z); a[3]=f2b(f0.w);
        }
        af[9] = a;
    } else {
        const unsigned short* Ab = (const unsigned short*)emb + (size_t)xq * EMB;
        #pragma unroll
        for (int kk = 0; kk < 9; ++kk) {
            int k = kk * 32 + quad * 8;
            short8 a;
            ((uint2*)&a)[0] = *(const uint2*)(Ab + k);
            ((uint2*)&a)[1] = *(const uint2*)(Ab + k + 4);
            af[kk] = a;
        }
        short8 a = {0,0,0,0,0,0,0,0};
        if (quad == 0) {
            ((uint2*)&a)[0] = *(const uint2*)(Ab + 288);
            ((uint2*)&a)[1] = *(const uint2*)(Ab + 292);
        } else if (quad == 1) {
            ((uint2*)&a)[0] = *(const uint2*)(Ab + 296);
        }
        af[9] = a;
    }
}

// ---------------------------------------------------------------------------
// detect: bf16 (mode=0) vs fp32 (mode=1) input buffers. Zeroes both flag sets.
// ctl ints: [0]=mode, flagsA=ctl+64 (64 flags stride 4), flagsB=ctl+320.
// ---------------------------------------------------------------------------
__global__ __launch_bounds__(64)
void detect_kernel(const void* __restrict__ W, int* __restrict__ ctl)
{
    const int tid = threadIdx.x;
    const unsigned short* p = (const unsigned short*)W;
    int bad = 0;
    for (int i = tid; i < 1024; i += 64) {
        float v = b2f(p[2 * i]);
        if (!(v > -0.5f && v < 0.5f)) bad++;
    }
    for (int off = 32; off; off >>= 1) bad += __shfl_down(bad, off);
    if (tid == 0) ctl[0] = (bad > 16) ? 1 : 0;
    for (int i = 64 + tid; i < 576; i += 64) ctl[i] = 0;
}

// ---------------------------------------------------------------------------
// scan2: both recurrences pipelined, layer-0 input projection fused in.
// ---------------------------------------------------------------------------
__global__ __launch_bounds__(256)
void scan2_kernel(const int*  __restrict__ xidx,
                  const void* __restrict__ emb,
                  const void* __restrict__ Wih0, const void* __restrict__ bih0,
                  unsigned short* __restrict__ preB,   // pre1 (block layout)
                  unsigned short* __restrict__ h1B,    // 2-slab ring
                  unsigned short* __restrict__ h2B,    // 2-slab ring
                  const void* __restrict__ Whh0, const void* __restrict__ bhh0,
                  const void* __restrict__ Wih1, const void* __restrict__ bih1,
                  const void* __restrict__ Whh1, const void* __restrict__ bhh1,
                  int* __restrict__ ctl)
{
    const int mode = ctl[0];
    const int gbx  = blockIdx.x;
    const int L    = gbx >> 6;           // 0: layer0(+proj+fuse), 1: layer1
    const int bx   = gbx & 63;
    const int n0   = bx * 16;
    int* flagsA    = ctl + 64;
    int* flagsSelf = ctl + (L ? 320 : 64);
    unsigned short* hB = L ? h2B : h1B;
    const void* Whh  = L ? Whh1 : Whh0;
    const void* bhhv = L ? bhh1 : bhh0;

    __shared__ unsigned short Wl[16 * 1032];
    __shared__ unsigned short Wn[16 * 1032];
    __shared__ unsigned short Wp[16 * 328];       // Wih0 slice (L0), pad zeroed
    __shared__ __align__(16) unsigned short hTile[1024];
    __shared__ __align__(16) unsigned short pTile[1024];
    const int tid = threadIdx.x;

    if (mode) {
        const float* Wf = (const float*)Whh;
        for (int i = tid; i < 16 * 256; i += 256) {
            int nl = i >> 8, c = i & 255;
            float4 f = *(const float4*)(Wf + ((size_t)(n0 + nl) << 10) + c * 4);
            unsigned short* d = &Wl[nl * 1032 + c * 4];
            d[0] = f2b(f.x); d[1] = f2b(f.y); d[2] = f2b(f.z); d[3] = f2b(f.w);
        }
        if (L == 0) {
            const float* Wg = (const float*)Wih1;
            for (int i = tid; i < 16 * 256; i += 256) {
                int nl = i >> 8, c = i & 255;
                float4 f = *(const float4*)(Wg + ((size_t)(n0 + nl) << 10) + c * 4);
                unsigned short* d = &Wn[nl * 1032 + c * 4];
                d[0] = f2b(f.x); d[1] = f2b(f.y); d[2] = f2b(f.z); d[3] = f2b(f.w);
            }
            const float* Wf2 = (const float*)Wih0;
            for (int i = tid; i < 16 * 75; i += 256) {
                int nl = i / 75, c = i - nl * 75;
                float4 f = *(const float4*)(Wf2 + (size_t)(n0 + nl) * EMB + c * 4);
                unsigned short* d = &Wp[nl * 328 + c * 4];
                d[0] = f2b(f.x); d[1] = f2b(f.y); d[2] = f2b(f.z); d[3] = f2b(f.w);
            }
        }
    } else {
        const unsigned short* Wb = (const unsigned short*)Whh;
        for (int i = tid; i < 16 * 128; i += 256) {
            int nl = i >> 7, c = i & 127;
            *(short8*)&Wl[nl * 1032 + c * 8] =
                *(const short8*)(Wb + ((size_t)(n0 + nl) << 10) + c * 8);
        }
        if (L == 0) {
            const unsigned short* Wg = (const unsigned short*)Wih1;
            for (int i = tid; i < 16 * 128; i += 256) {
                int nl = i >> 7, c = i & 127;
                *(short8*)&Wn[nl * 1032 + c * 8] =
                    *(const short8*)(Wg + ((size_t)(n0 + nl) << 10) + c * 8);
            }
            const unsigned short* Wb2 = (const unsigned short*)Wih0;
            for (int i = tid; i < 16 * 300; i += 256) {
                int nl = i / 300, c = i - nl * 300;
                Wp[nl * 328 + c] = Wb2[(size_t)(n0 + nl) * EMB + c];
            }
        }
    }
    if (L == 0) {   // zero Wp pad cols 300..327 (unmasked tail MFMA reads them)
        for (int i = tid; i < 16 * 28; i += 256) {
            int nl = i / 28, c = 300 + (i - nl * 28);
            Wp[nl * 328 + c] = 0;
        }
    }
    __syncthreads();

    const int wave = tid >> 6, lane = tid & 63;
    const int quad = lane >> 4, ln = lane & 15;
    const int brow = wave * 16 + ln;
    const int ncol = n0 + ln;
    float bvf = mode ? ((const float*)bhhv)[ncol]
                     : b2f(((const unsigned short*)bhhv)[ncol]);
    if (L == 0)     // fold bih0 in: h1 = tanh(pre0_f32 + rec + bih0 + bhh0)
        bvf += mode ? ((const float*)bih0)[ncol]
                    : b2f(((const unsigned short*)bih0)[ncol]);
    const float bnf = (L == 0)
        ? (mode ? ((const float*)bih1)[ncol]
                : b2f(((const unsigned short*)bih1)[ncol]))
        : 0.f;
    const int b0 = wave * 16 + quad * 4;
    const unsigned short* wl = &Wl[ln * 1032 + quad * 8];
    const unsigned short* wn = &Wn[ln * 1032 + quad * 8];
    const unsigned short* wp = &Wp[ln * 328 + quad * 8];
    // per-lane base offset within an h slab: k = kk*32 + quad*8
    const int hoff = (quad >> 1) * 1024 + brow * 16 + (quad & 1) * 8;

    // A-gather software pipeline (L0): af = fragments for step t,
    // xq1 = emb row index for step t+1.
    short8 af[10];
    int xq1 = 0;
    if (L == 0) {
        int xq0 = xidx[brow * TT + 0];
        prefetch_A(emb, mode, xq0, quad, af);
        xq1 = xidx[brow * TT + 1];
    }

    for (int t = 0; t < TT; ++t) {
        floatx4 acc  = {0.f, 0.f, 0.f, 0.f};
        floatx4 acc2 = {0.f, 0.f, 0.f, 0.f};
        short8 afn[10];
        int xq2 = 0;
        float fin0, fin1, fin2, fin3;

        if (L == 0) {
            // pre0[t] from prefetched fragments (pure LDS+MFMA, no new loads)
            floatx4 acc0 = {0.f, 0.f, 0.f, 0.f};
            #pragma unroll
            for (int kk = 0; kk < 10; ++kk) {
                short8 b = *(const short8*)(wp + kk * 32);
                acc0 = __builtin_amdgcn_mfma_f32_16x16x32_bf16(af[kk], b, acc0, 0, 0, 0);
            }
            // prefetch next step's fragments (compiler loads, issued BEFORE
            // the asm h-loads -> older in vmcnt queue -> WAIT_VM16 safe)
            if (t + 1 < TT) {
                prefetch_A(emb, mode, xq1, quad, afn);
                if (t + 2 < TT) xq2 = xidx[brow * TT + t + 2];
            }
            if (t > 0) {
                short8 a[32];
                const unsigned short* hp = hB + (size_t)((t - 1) & 1) * 65536 + hoff;
                #pragma unroll
                for (int kk = 0; kk < 32; ++kk)
                    asm volatile("global_load_dwordx4 %0, %1, off sc1"
                                 : "=v"(a[kk])
                                 : "v"(hp + (size_t)kk * 2048) : "memory");
                WAIT_VM16(16, a);   // a[0..15] done
                #pragma unroll
                for (int kk = 0; kk < 16; ++kk) {
                    short8 b  = *(const short8*)(wl + kk * 32);
                    short8 bn = *(const short8*)(wn + kk * 32);
                    acc  = __builtin_amdgcn_mfma_f32_16x16x32_bf16(a[kk], b,  acc,  0, 0, 0);
                    acc2 = __builtin_amdgcn_mfma_f32_16x16x32_bf16(a[kk], bn, acc2, 0, 0, 0);
                }
                WAIT_VM16(0, (a + 16));
                #pragma unroll
                for (int kk = 16; kk < 32; ++kk) {
                    short8 b  = *(const short8*)(wl + kk * 32);
                    short8 bn = *(const short8*)(wn + kk * 32);
                    acc  = __builtin_amdgcn_mfma_f32_16x16x32_bf16(a[kk], b,  acc,  0, 0, 0);
                    acc2 = __builtin_amdgcn_mfma_f32_16x16x32_bf16(a[kk], bn, acc2, 0, 0, 0);
                }
            }
            fin0 = acc[0] + acc0[0] + bvf;
            fin1 = acc[1] + acc0[1] + bvf;
            fin2 = acc[2] + acc0[2] + bvf;
            fin3 = acc[3] + acc0[3] + bvf;
        } else {
            const unsigned short* pp = preB + (size_t)t * 65536 + (size_t)bx * 1024
                                            + (size_t)b0 * 16 + ln;
            unsigned int pr0, pr1, pr2, pr3;
            // producer wait FIRST: no asm-load results live across this loop.
            {
                const int* fp = &flagsA[bx * 4];
                int v;
                do {
                    asm volatile("global_load_dword %0, %1, off sc1\n\t"
                                 "s_waitcnt vmcnt(0)"
                                 : "=v"(v) : "v"(fp) : "memory");
                } while (v < t + 2);
            }
            if (t > 0) {
                short8 a[32];
                const unsigned short* hp = hB + (size_t)((t - 1) & 1) * 65536 + hoff;
                #pragma unroll
                for (int kk = 0; kk < 32; ++kk)
                    asm volatile("global_load_dwordx4 %0, %1, off sc1"
                                 : "=v"(a[kk])
                                 : "v"(hp + (size_t)kk * 2048) : "memory");
                WAIT_VM16(16, a);    // a[0..15] done
                #pragma unroll
                for (int kk = 0; kk < 16; ++kk) {
                    short8 b = *(const short8*)(wl + kk * 32);
                    acc = __builtin_amdgcn_mfma_f32_16x16x32_bf16(a[kk], b, acc, 0, 0, 0);
                }
                // pre1[t] (sc1, cross-XCD). Issued after a[16..31]: vmcnt(4)
                // below completes all 16 older a-loads first.
                asm volatile("global_load_ushort %0, %1, off sc1"
                             : "=v"(pr0) : "v"(pp) : "memory");
                asm volatile("global_load_ushort %0, %1, off offset:32 sc1"
                             : "=v"(pr1) : "v"(pp) : "memory");
                asm volatile("global_load_ushort %0, %1, off offset:64 sc1"
                             : "=v"(pr2) : "v"(pp) : "memory");
                asm volatile("global_load_ushort %0, %1, off offset:96 sc1"
                             : "=v"(pr3) : "v"(pp) : "memory");
                WAIT_VM16(4, (a + 16));   // a[16..31] done; pr* in flight
                #pragma unroll
                for (int kk = 16; kk < 32; ++kk) {
                    short8 b = *(const short8*)(wl + kk * 32);
                    acc = __builtin_amdgcn_mfma_f32_16x16x32_bf16(a[kk], b, acc, 0, 0, 0);
                }
            } else {
                asm volatile("global_load_ushort %0, %1, off sc1"
                             : "=v"(pr0) : "v"(pp) : "memory");
                asm volatile("global_load_ushort %0, %1, off offset:32 sc1"
                             : "=v"(pr1) : "v"(pp) : "memory");
                asm volatile("global_load_ushort %0, %1, off offset:64 sc1"
                             : "=v"(pr2) : "v"(pp) : "memory");
                asm volatile("global_load_ushort %0, %1, off offset:96 sc1"
                             : "=v"(pr3) : "v"(pp) : "memory");
            }
            // bind pr* at a real vmcnt(0), immediately before use
            asm volatile("s_waitcnt vmcnt(0)"
                         : "+v"(pr0), "+v"(pr1), "+v"(pr2), "+v"(pr3) :: "memory");
            fin0 = acc[0] + b2f(pr0) + bvf;
            fin1 = acc[1] + b2f(pr1) + bvf;
            fin2 = acc[2] + b2f(pr2) + bvf;
            fin3 = acc[3] + b2f(pr3) + bvf;
        }

        hTile[(b0 + 0) * 16 + ln] = f2b(tanhf(fin0));
        hTile[(b0 + 1) * 16 + ln] = f2b(tanhf(fin1));
        hTile[(b0 + 2) * 16 + ln] = f2b(tanhf(fin2));
        hTile[(b0 + 3) * 16 + ln] = f2b(tanhf(fin3));
        if (L == 0 && t > 0) {
            pTile[(b0 + 0) * 16 + ln] = f2b(acc2[0] + bnf);
            pTile[(b0 + 1) * 16 + ln] = f2b(acc2[1] + bnf);
            pTile[(b0 + 2) * 16 + ln] = f2b(acc2[2] + bnf);
            pTile[(b0 + 3) * 16 + ln] = f2b(acc2[3] + bnf);
        }
        __syncthreads();
        if (tid < 128) {   // 2 KB contiguous -> 32 full 64B lines each
            short8 hv = *(const short8*)&hTile[tid * 8];
            asm volatile("global_store_dwordx4 %0, %1, off sc1"
                         :: "v"(hB + (size_t)(t & 1) * 65536 + (size_t)bx * 1024 + tid * 8),
                            "v"(hv) : "memory");
            if (L == 0 && t > 0) {
                short8 pv = *(const short8*)&pTile[tid * 8];
                asm volatile("global_store_dwordx4 %0, %1, off sc1"
                             :: "v"(preB + (size_t)(t - 1) * 65536 + (size_t)bx * 1024 + tid * 8),
                                "v"(pv) : "memory");
            }
        }
        if (t < TT - 1) {
            asm volatile("s_waitcnt vmcnt(0)" ::: "memory");
            __syncthreads();
            if (tid == 0) {
                int tv = t + 1;
                asm volatile("global_store_dword %0, %1, off sc1"
                             :: "v"(&flagsSelf[bx * 4]), "v"(tv) : "memory");
            }
            if (tid < 64) {
                const int* fp = &flagsSelf[tid * 4];
                int v;
                do {
                    asm volatile("global_load_dword %0, %1, off sc1\n\t"
                                 "s_waitcnt vmcnt(0)"
                                 : "=v"(v) : "v"(fp) : "memory");
                } while (__any(v < t + 1));
            }
            __syncthreads();
        }
        // rotate the A-gather pipeline (register moves, no memory)
        if (L == 0 && t + 1 < TT) {
            #pragma unroll
            for (int j = 0; j < 10; ++j) af[j] = afn[j];
            xq1 = xq2;
        }
    }

    if (L == 0) {   // tail: pre1[511] needs full h1[511] -> one barrier round
        asm volatile("s_waitcnt vmcnt(0)" ::: "memory");
        __syncthreads();
        if (tid == 0) {
            int tv = TT;   // releases layer-1 t=510
            asm volatile("global_store_dword %0, %1, off sc1"
                         :: "v"(&flagsSelf[bx * 4]), "v"(tv) : "memory");
        }
        if (tid < 64) {
            const int* fp = &flagsSelf[tid * 4];
            int v;
            do {
                asm volatile("global_load_dword %0, %1, off sc1\n\t"
                             "s_waitcnt vmcnt(0)"
                             : "=v"(v) : "v"(fp) : "memory");
            } while (__any(v < TT));
        }
        __syncthreads();

        const unsigned short* hp = hB + (size_t)((TT - 1) & 1) * 65536 + hoff;
        short8 a[32];
        floatx4 acc2 = {0.f, 0.f, 0.f, 0.f};
        #pragma unroll
        for (int kk = 0; kk < 32; ++kk)
            asm volatile("global_load_dwordx4 %0, %1, off sc1"
                         : "=v"(a[kk])
                         : "v"(hp + (size_t)kk * 2048) : "memory");
        WAIT_VM16(16, a);
        #pragma unroll
        for (int kk = 0; kk < 16; ++kk) {
            short8 bn = *(const short8*)(wn + kk * 32);
            acc2 = __builtin_amdgcn_mfma_f32_16x16x32_bf16(a[kk], bn, acc2, 0, 0, 0);
        }
        WAIT_VM16(0, (a + 16));
        #pragma unroll
        for (int kk = 16; kk < 32; ++kk) {
            short8 bn = *(const short8*)(wn + kk * 32);
            acc2 = __builtin_amdgcn_mfma_f32_16x16x32_bf16(a[kk], bn, acc2, 0, 0, 0);
        }
        pTile[(b0 + 0) * 16 + ln] = f2b(acc2[0] + bnf);
        pTile[(b0 + 1) * 16 + ln] = f2b(acc2[1] + bnf);
        pTile[(b0 + 2) * 16 + ln] = f2b(acc2[2] + bnf);
        pTile[(b0 + 3) * 16 + ln] = f2b(acc2[3] + bnf);
        __syncthreads();
        if (tid < 128) {
            short8 pv = *(const short8*)&pTile[tid * 8];
            asm volatile("global_store_dwordx4 %0, %1, off sc1"
                         :: "v"(preB + (size_t)(TT - 1) * 65536 + (size_t)bx * 1024 + tid * 8),
                            "v"(pv) : "memory");
        }
        asm volatile("s_waitcnt vmcnt(0)" ::: "memory");
        __syncthreads();
        if (tid == 0) {
            int tv = TT + 1;   // releases layer-1 t=511
            asm volatile("global_store_dword %0, %1, off sc1"
                         :: "v"(&flagsSelf[bx * 4]), "v"(tv) : "memory");
        }
    }
}

// ---------------------------------------------------------------------------
// fc: out[b] = sigmoid(dot(h2[T-1][b], Wfc) + bfc) -- h2 ring slab (TT-1)&1
// ---------------------------------------------------------------------------
__global__ __launch_bounds__(1024)
void fc_kernel(const unsigned short* __restrict__ h,
               const void* __restrict__ Wfc,
               const void* __restrict__ bfc,
               float* __restrict__ out,
               const int* __restrict__ ctl)
{
    const int mode = ctl[0];
    const int tid = threadIdx.x;
    const int b = tid >> 4, sub = tid & 15;
    const unsigned short* hr = h + (size_t)((TT - 1) & 1) * 65536 + b * 16 + sub;
    float s = 0.f;
    for (int j = 0; j < 64; ++j) {          // k = j*16 + sub
        float w = mode ? ((const float*)Wfc)[j * 16 + sub]
                       : b2f(((const unsigned short*)Wfc)[j * 16 + sub]);
        s += b2f(hr[(size_t)j * 1024]) * w;
    }
    for (int off = 8; off; off >>= 1)
        s += __shfl_down(s, off, 16);
    if (sub == 0) {
        float bv = mode ? ((const float*)bfc)[0]
                        : b2f(((const unsigned short*)bfc)[0]);
        out[b] = 1.f / (1.f + expf(-(s + bv)));
    }
}

// ---------------------------------------------------------------------------
extern "C" void kernel_launch(void* const* d_in, const int* in_sizes, int n_in,
                              void* d_out, int out_size, void* d_ws, size_t ws_size,
                              hipStream_t stream)
{
    const int*  x    = (const int*)d_in[0];
    const void* emb  = d_in[1];
    const void* Wih0 = d_in[2];
    const void* Whh0 = d_in[3];
    const void* bih0 = d_in[4];
    const void* bhh0 = d_in[5];
    const void* Wih1 = d_in[6];
    const void* Whh1 = d_in[7];
    const void* bih1 = d_in[8];
    const void* bhh1 = d_in[9];
    const void* Wfc  = d_in[10];
    const void* bfc  = d_in[11];
    float* out = (float*)d_out;

    char* ws = (char*)d_ws;
    int*            ctl  = (int*)ws;                              // 4 KiB
    unsigned short* pre  = (unsigned short*)(ws + 4096);          // 64 MiB (pre1)
    unsigned short* h1   = (unsigned short*)(ws + 4096 + (size_t)67108864); // 256 KiB ring
    unsigned short* h2   = h1 + 2 * 65536;                        // 256 KiB ring

    // dtype detect + flag zeroing
    detect_kernel<<<dim3(1), dim3(64), 0, stream>>>(Whh0, ctl);
    // both recurrences, software-pipelined; layer-0 input projection fused
    scan2_kernel<<<dim3(128), dim3(256), 0, stream>>>(
        x, emb, Wih0, bih0, pre, h1, h2,
        Whh0, bhh0, Wih1, bih1, Whh1, bhh1, ctl);
    // final FC + sigmoid
    fc_kernel<<<dim3(1), dim3(1024), 0, stream>>>(h2, Wfc, bfc, out, ctl);
}

// Round 13
// 2799.855 us; speedup vs baseline: 1.5245x; 1.5245x over previous
//
#include <hip/hip_runtime.h>
#include <hip/hip_bf16.h>

#define VOCAB 50000
#define EMB   300
#define HID   1024
#define TT    512
#define BB    64

// Block layout for pre: [t][kb=64][row=64][c=16] bf16; per-t slab = 65536 shorts.
// h1/h2 are 2-slab rings (slab = t&1); the per-step all-to-all flag barrier
// guarantees ring-2 reuse safety.
//
// Pipelined scan: 128 WGs. WGs 0..63 = layer 0 (FUSE: also emits
// pre1[t-1] = h1[t-1]*W_ih1^T + b_ih1, via LDS tile -> full-line sc1 stores,
// drained before flagA[bx]=t+1). WGs 64..127 = layer 1, step t gated only on
// flagsA[bx] >= t+2. A never waits on B -> no deadlock; B trails ~2 steps.
//
// proj: one WG per t (512 WGs). Stage the 64 emb rows ONCE in LDS (bf16),
// then loop 64 col-blocks staging only the 16x300 W slice (L2-resident);
// outputs assembled in an LDS tile -> full-64B-line stores. This removes the
// 64x emb re-gather the old (nb,mb) grid did.
//
// NOTE: asm "=v" load results must NEVER be live across a variable-trip loop
// and keep short straight-line ranges (allocator may spill them before the
// data lands -> garbage).

typedef __attribute__((ext_vector_type(8))) short short8;
typedef __attribute__((ext_vector_type(4))) float floatx4;

__device__ inline float b2f(unsigned int u) {
    union { unsigned int i; float f; } v; v.i = u << 16; return v.f;
}
__device__ inline unsigned short f2b(float f) {
    __hip_bfloat16 h = __float2bfloat16(f);
    return *reinterpret_cast<unsigned short*>(&h);
}

// Wait until only N of the outstanding vector loads remain, binding the first
// 16 fragments "+v" so the compiler cannot consume them earlier.
#define WAIT_VM16(N, A) asm volatile("s_waitcnt vmcnt(" #N ")"              \
    : "+v"((A)[0]), "+v"((A)[1]), "+v"((A)[2]), "+v"((A)[3]),               \
      "+v"((A)[4]), "+v"((A)[5]), "+v"((A)[6]), "+v"((A)[7]),               \
      "+v"((A)[8]), "+v"((A)[9]), "+v"((A)[10]), "+v"((A)[11]),             \
      "+v"((A)[12]), "+v"((A)[13]), "+v"((A)[14]), "+v"((A)[15])            \
    :: "memory")

// ---------------------------------------------------------------------------
// detect: bf16 (mode=0) vs fp32 (mode=1) input buffers. Zeroes both flag sets.
// ctl ints: [0]=mode, flagsA=ctl+64 (64 flags stride 4), flagsB=ctl+320.
// ---------------------------------------------------------------------------
__global__ __launch_bounds__(64)
void detect_kernel(const void* __restrict__ W, int* __restrict__ ctl)
{
    const int tid = threadIdx.x;
    const unsigned short* p = (const unsigned short*)W;
    int bad = 0;
    for (int i = tid; i < 1024; i += 64) {
        float v = b2f(p[2 * i]);
        if (!(v > -0.5f && v < 0.5f)) bad++;
    }
    for (int off = 32; off; off >>= 1) bad += __shfl_down(bad, off);
    if (tid == 0) ctl[0] = (bad > 16) ? 1 : 0;
    for (int i = 64 + tid; i < 576; i += 64) ctl[i] = 0;
}

// ---------------------------------------------------------------------------
// proj: pre0[t*64+b][n] = bf16( emb[x[b][t]]·W_ih0^T + b_ih0 ), block layout.
// One WG per t: emb rows staged once, col-blocks looped.
// Stride 328 shorts (656 B = 164 dwords, 164%32=4) -> 2-way LDS aliasing max.
// Pads (cols 300..327) zeroed once; K-loop runs 10 unmasked MFMAs (k<320).
// ---------------------------------------------------------------------------
__global__ __launch_bounds__(256)
void proj_kernel(const int*  __restrict__ xidx,
                 const void* __restrict__ emb,
                 const void* __restrict__ W,
                 const void* __restrict__ bias,
                 unsigned short* __restrict__ C,    // block layout bf16
                 const int* __restrict__ ctl)
{
    const int mode = ctl[0];
    const int t   = blockIdx.x;
    const int tid = threadIdx.x;
    __shared__ unsigned short eT[64 * 328];          // 41984 B
    __shared__ unsigned short Wl[16 * 328];          // 10496 B
    __shared__ __align__(16) unsigned short oT[1024];// 2 KB
    __shared__ int xqL[64];

    if (tid < 64) xqL[tid] = xidx[tid * TT + t];
    for (int i = tid; i < 64 * 28; i += 256) {       // zero eT pad
        int b = i / 28, c = 300 + i % 28;
        eT[b * 328 + c] = 0;
    }
    for (int i = tid; i < 16 * 28; i += 256) {       // zero Wl pad (stays 0)
        int nl = i / 28, c = 300 + i % 28;
        Wl[nl * 328 + c] = 0;
    }
    __syncthreads();

    // stage 64 emb rows as bf16 (once)
    if (mode) {
        for (int i = tid; i < 64 * 75; i += 256) {   // 75 float4 per row
            int b = i / 75, seg = i % 75;
            const float* src = (const float*)emb
                             + (size_t)xqL[b] * EMB + seg * 4;
            float4 f = *(const float4*)src;
            unsigned short* d = &eT[b * 328 + seg * 4];
            d[0] = f2b(f.x); d[1] = f2b(f.y); d[2] = f2b(f.z); d[3] = f2b(f.w);
        }
    } else {
        for (int i = tid; i < 64 * 75; i += 256) {   // 75 uint2 (4 shorts) per row
            int b = i / 75, seg = i % 75;
            const unsigned short* src = (const unsigned short*)emb
                                      + (size_t)xqL[b] * EMB + seg * 4;
            *(uint2*)&eT[b * 328 + seg * 4] = *(const uint2*)src;
        }
    }

    const int wave = tid >> 6, lane = tid & 63;
    const int quad = lane >> 4, ln = lane & 15;

    for (int nb = 0; nb < 64; ++nb) {
        __syncthreads();   // Wl/oT safe to overwrite (prev readers done)
        if (mode) {
            const float* Wf = (const float*)W;
            for (int i = tid; i < 16 * 75; i += 256) {
                int nl = i / 75, seg = i % 75;
                float4 f = *(const float4*)(Wf + (size_t)(nb * 16 + nl) * EMB + seg * 4);
                unsigned short* d = &Wl[nl * 328 + seg * 4];
                d[0] = f2b(f.x); d[1] = f2b(f.y); d[2] = f2b(f.z); d[3] = f2b(f.w);
            }
        } else {
            const unsigned short* Wb = (const unsigned short*)W;
            for (int i = tid; i < 16 * 75; i += 256) {
                int nl = i / 75, seg = i % 75;
                *(uint2*)&Wl[nl * 328 + seg * 4] =
                    *(const uint2*)(Wb + (size_t)(nb * 16 + nl) * EMB + seg * 4);
            }
        }
        __syncthreads();

        floatx4 acc = {0.f, 0.f, 0.f, 0.f};
        #pragma unroll
        for (int kk = 0; kk < 10; ++kk) {
            int k = kk * 32 + quad * 8;
            short8 a = *(const short8*)&eT[(wave * 16 + ln) * 328 + k];
            short8 b = *(const short8*)&Wl[ln * 328 + k];
            acc = __builtin_amdgcn_mfma_f32_16x16x32_bf16(a, b, acc, 0, 0, 0);
        }
        const int col = nb * 16 + ln;
        const float bvf = mode ? ((const float*)bias)[col]
                               : b2f(((const unsigned short*)bias)[col]);
        oT[(wave * 16 + quad * 4 + 0) * 16 + ln] = f2b(acc[0] + bvf);
        oT[(wave * 16 + quad * 4 + 1) * 16 + ln] = f2b(acc[1] + bvf);
        oT[(wave * 16 + quad * 4 + 2) * 16 + ln] = f2b(acc[2] + bvf);
        oT[(wave * 16 + quad * 4 + 3) * 16 + ln] = f2b(acc[3] + bvf);
        __syncthreads();
        if (tid < 128) {   // 2 KB contiguous -> 32 full 64B lines
            short8 hv = *(const short8*)&oT[tid * 8];
            *(short8*)(C + ((size_t)t * 64 + nb) * 1024 + tid * 8) = hv;
        }
    }
}

// ---------------------------------------------------------------------------
// scan2: both recurrences pipelined. 128 persistent WGs x 256 thr.
//   WG 0..63   (L=0): h1[t]=tanh(pre0[t]+h1[t-1]Whh0^T+bhh0), FUSE pre1[t-1].
//   WG 64..127 (L=1): h2[t]=tanh(pre1[t]+h2[t-1]Whh1^T+bhh1), gated on flagsA.
// ---------------------------------------------------------------------------
__global__ __launch_bounds__(256)
void scan2_kernel(unsigned short* __restrict__ preB,   // block layout bf16
                  unsigned short* __restrict__ h1B,    // 2-slab ring
                  unsigned short* __restrict__ h2B,    // 2-slab ring
                  const void* __restrict__ Whh0, const void* __restrict__ bhh0,
                  const void* __restrict__ Wih1, const void* __restrict__ bih1,
                  const void* __restrict__ Whh1, const void* __restrict__ bhh1,
                  int* __restrict__ ctl)
{
    const int mode = ctl[0];
    const int gbx  = blockIdx.x;
    const int L    = gbx >> 6;           // 0: layer0(+fuse), 1: layer1
    const int bx   = gbx & 63;
    const int n0   = bx * 16;
    int* flagsA    = ctl + 64;
    int* flagsSelf = ctl + (L ? 320 : 64);
    unsigned short* hB = L ? h2B : h1B;
    const void* Whh  = L ? Whh1 : Whh0;
    const void* bhhv = L ? bhh1 : bhh0;

    __shared__ unsigned short Wl[16 * 1032];
    __shared__ unsigned short Wn[16 * 1032];
    __shared__ __align__(16) unsigned short hTile[1024];
    __shared__ __align__(16) unsigned short pTile[1024];
    const int tid = threadIdx.x;

    if (mode) {
        const float* Wf = (const float*)Whh;
        for (int i = tid; i < 16 * 256; i += 256) {
            int nl = i >> 8, c = i & 255;
            float4 f = *(const float4*)(Wf + ((size_t)(n0 + nl) << 10) + c * 4);
            unsigned short* d = &Wl[nl * 1032 + c * 4];
            d[0] = f2b(f.x); d[1] = f2b(f.y); d[2] = f2b(f.z); d[3] = f2b(f.w);
        }
        if (L == 0) {
            const float* Wg = (const float*)Wih1;
            for (int i = tid; i < 16 * 256; i += 256) {
                int nl = i >> 8, c = i & 255;
                float4 f = *(const float4*)(Wg + ((size_t)(n0 + nl) << 10) + c * 4);
                unsigned short* d = &Wn[nl * 1032 + c * 4];
                d[0] = f2b(f.x); d[1] = f2b(f.y); d[2] = f2b(f.z); d[3] = f2b(f.w);
            }
        }
    } else {
        const unsigned short* Wb = (const unsigned short*)Whh;
        for (int i = tid; i < 16 * 128; i += 256) {
            int nl = i >> 7, c = i & 127;
            *(short8*)&Wl[nl * 1032 + c * 8] =
                *(const short8*)(Wb + ((size_t)(n0 + nl) << 10) + c * 8);
        }
        if (L == 0) {
            const unsigned short* Wg = (const unsigned short*)Wih1;
            for (int i = tid; i < 16 * 128; i += 256) {
                int nl = i >> 7, c = i & 127;
                *(short8*)&Wn[nl * 1032 + c * 8] =
                    *(const short8*)(Wg + ((size_t)(n0 + nl) << 10) + c * 8);
            }
        }
    }
    __syncthreads();

    const int wave = tid >> 6, lane = tid & 63;
    const int quad = lane >> 4, ln = lane & 15;
    const int brow = wave * 16 + ln;
    const int ncol = n0 + ln;
    const float bvf = mode ? ((const float*)bhhv)[ncol]
                           : b2f(((const unsigned short*)bhhv)[ncol]);
    const float bnf = (L == 0)
        ? (mode ? ((const float*)bih1)[ncol]
                : b2f(((const unsigned short*)bih1)[ncol]))
        : 0.f;
    const int b0 = wave * 16 + quad * 4;
    const unsigned short* wl = &Wl[ln * 1032 + quad * 8];
    const unsigned short* wn = &Wn[ln * 1032 + quad * 8];
    // per-lane base offset within an h slab: k = kk*32 + quad*8
    const int hoff = (quad >> 1) * 1024 + brow * 16 + (quad & 1) * 8;

    for (int t = 0; t < TT; ++t) {
        const unsigned short* pp = preB + (size_t)t * 65536 + (size_t)bx * 1024
                                        + (size_t)b0 * 16 + ln;
        unsigned int pr0, pr1, pr2, pr3;
        floatx4 acc  = {0.f, 0.f, 0.f, 0.f};
        floatx4 acc2 = {0.f, 0.f, 0.f, 0.f};

        if (L == 0) {
            // pre0[t]: written by proj (previous kernel) -> plain loads fine.
            pr0 = pp[0]; pr1 = pp[16]; pr2 = pp[32]; pr3 = pp[48];
            if (t > 0) {
                short8 a[32];
                const unsigned short* hp = hB + (size_t)((t - 1) & 1) * 65536 + hoff;
                #pragma unroll
                for (int kk = 0; kk < 32; ++kk)
                    asm volatile("global_load_dwordx4 %0, %1, off sc1"
                                 : "=v"(a[kk])
                                 : "v"(hp + (size_t)kk * 2048) : "memory");
                WAIT_VM16(16, a);   // a[0..15] done
                #pragma unroll
                for (int kk = 0; kk < 16; ++kk) {
                    short8 b  = *(const short8*)(wl + kk * 32);
                    short8 bn = *(const short8*)(wn + kk * 32);
                    acc  = __builtin_amdgcn_mfma_f32_16x16x32_bf16(a[kk], b,  acc,  0, 0, 0);
                    acc2 = __builtin_amdgcn_mfma_f32_16x16x32_bf16(a[kk], bn, acc2, 0, 0, 0);
                }
                WAIT_VM16(0, (a + 16));
                #pragma unroll
                for (int kk = 16; kk < 32; ++kk) {
                    short8 b  = *(const short8*)(wl + kk * 32);
                    short8 bn = *(const short8*)(wn + kk * 32);
                    acc  = __builtin_amdgcn_mfma_f32_16x16x32_bf16(a[kk], b,  acc,  0, 0, 0);
                    acc2 = __builtin_amdgcn_mfma_f32_16x16x32_bf16(a[kk], bn, acc2, 0, 0, 0);
                }
            }
        } else {
            // producer wait FIRST: no asm-load results may be live across a
            // variable-trip loop (spill-before-arrival hazard).
            {
                const int* fp = &flagsA[bx * 4];
                int v;
                do {
                    asm volatile("global_load_dword %0, %1, off sc1\n\t"
                                 "s_waitcnt vmcnt(0)"
                                 : "=v"(v) : "v"(fp) : "memory");
                } while (v < t + 2);
            }
            if (t > 0) {
                short8 a[32];
                const unsigned short* hp = hB + (size_t)((t - 1) & 1) * 65536 + hoff;
                #pragma unroll
                for (int kk = 0; kk < 32; ++kk)
                    asm volatile("global_load_dwordx4 %0, %1, off sc1"
                                 : "=v"(a[kk])
                                 : "v"(hp + (size_t)kk * 2048) : "memory");
                WAIT_VM16(16, a);    // a[0..15] done (16 of 32 remain)
                #pragma unroll
                for (int kk = 0; kk < 16; ++kk) {
                    short8 b = *(const short8*)(wl + kk * 32);
                    acc = __builtin_amdgcn_mfma_f32_16x16x32_bf16(a[kk], b, acc, 0, 0, 0);
                }
                // pre1[t] (sc1: written by layer-0 peer on another XCD).
                // Issued after a[16..31]; vmcnt counts in issue order, so
                // vmcnt(4) below completes all 16 older a-loads first.
                asm volatile("global_load_ushort %0, %1, off sc1"
                             : "=v"(pr0) : "v"(pp) : "memory");
                asm volatile("global_load_ushort %0, %1, off offset:32 sc1"
                             : "=v"(pr1) : "v"(pp) : "memory");
                asm volatile("global_load_ushort %0, %1, off offset:64 sc1"
                             : "=v"(pr2) : "v"(pp) : "memory");
                asm volatile("global_load_ushort %0, %1, off offset:96 sc1"
                             : "=v"(pr3) : "v"(pp) : "memory");
                WAIT_VM16(4, (a + 16));   // a[16..31] done; pr* still in flight
                #pragma unroll
                for (int kk = 16; kk < 32; ++kk) {
                    short8 b = *(const short8*)(wl + kk * 32);
                    acc = __builtin_amdgcn_mfma_f32_16x16x32_bf16(a[kk], b, acc, 0, 0, 0);
                }
            } else {
                asm volatile("global_load_ushort %0, %1, off sc1"
                             : "=v"(pr0) : "v"(pp) : "memory");
                asm volatile("global_load_ushort %0, %1, off offset:32 sc1"
                             : "=v"(pr1) : "v"(pp) : "memory");
                asm volatile("global_load_ushort %0, %1, off offset:64 sc1"
                             : "=v"(pr2) : "v"(pp) : "memory");
                asm volatile("global_load_ushort %0, %1, off offset:96 sc1"
                             : "=v"(pr3) : "v"(pp) : "memory");
            }
            // bind pr* at a real vmcnt(0), immediately before use
            asm volatile("s_waitcnt vmcnt(0)"
                         : "+v"(pr0), "+v"(pr1), "+v"(pr2), "+v"(pr3) :: "memory");
        }

        hTile[(b0 + 0) * 16 + ln] = f2b(tanhf(acc[0] + b2f(pr0) + bvf));
        hTile[(b0 + 1) * 16 + ln] = f2b(tanhf(acc[1] + b2f(pr1) + bvf));
        hTile[(b0 + 2) * 16 + ln] = f2b(tanhf(acc[2] + b2f(pr2) + bvf));
        hTile[(b0 + 3) * 16 + ln] = f2b(tanhf(acc[3] + b2f(pr3) + bvf));
        if (L == 0 && t > 0) {
            pTile[(b0 + 0) * 16 + ln] = f2b(acc2[0] + bnf);
            pTile[(b0 + 1) * 16 + ln] = f2b(acc2[1] + bnf);
            pTile[(b0 + 2) * 16 + ln] = f2b(acc2[2] + bnf);
            pTile[(b0 + 3) * 16 + ln] = f2b(acc2[3] + bnf);
        }
        __syncthreads();
        if (tid < 128) {   // 2 KB contiguous -> 32 full 64B lines each
            short8 hv = *(const short8*)&hTile[tid * 8];
            asm volatile("global_store_dwordx4 %0, %1, off sc1"
                         :: "v"(hB + (size_t)(t & 1) * 65536 + (size_t)bx * 1024 + tid * 8),
                            "v"(hv) : "memory");
            if (L == 0 && t > 0) {
                short8 pv = *(const short8*)&pTile[tid * 8];
                asm volatile("global_store_dwordx4 %0, %1, off sc1"
                             :: "v"(preB + (size_t)(t - 1) * 65536 + (size_t)bx * 1024 + tid * 8),
                                "v"(pv) : "memory");
            }
        }
        if (t < TT - 1) {
            asm volatile("s_waitcnt vmcnt(0)" ::: "memory");
            __syncthreads();
            if (tid == 0) {
                int tv = t + 1;
                asm volatile("global_store_dword %0, %1, off sc1"
                             :: "v"(&flagsSelf[bx * 4]), "v"(tv) : "memory");
            }
            if (tid < 64) {
                const int* fp = &flagsSelf[tid * 4];
                int v;
                do {
                    asm volatile("global_load_dword %0, %1, off sc1\n\t"
                                 "s_waitcnt vmcnt(0)"
                                 : "=v"(v) : "v"(fp) : "memory");
                } while (__any(v < t + 1));
            }
            __syncthreads();
        }
    }

    if (L == 0) {   // tail: pre1[511] needs full h1[511] -> one more barrier round
        asm volatile("s_waitcnt vmcnt(0)" ::: "memory");
        __syncthreads();
        if (tid == 0) {
            int tv = TT;   // also releases layer-1 t=510 (needs pre1[510])
            asm volatile("global_store_dword %0, %1, off sc1"
                         :: "v"(&flagsSelf[bx * 4]), "v"(tv) : "memory");
        }
        if (tid < 64) {
            const int* fp = &flagsSelf[tid * 4];
            int v;
            do {
                asm volatile("global_load_dword %0, %1, off sc1\n\t"
                             "s_waitcnt vmcnt(0)"
                             : "=v"(v) : "v"(fp) : "memory");
            } while (__any(v < TT));
        }
        __syncthreads();

        const unsigned short* hp = hB + (size_t)((TT - 1) & 1) * 65536 + hoff;
        short8 a[32];
        floatx4 acc2 = {0.f, 0.f, 0.f, 0.f};
        #pragma unroll
        for (int kk = 0; kk < 32; ++kk)
            asm volatile("global_load_dwordx4 %0, %1, off sc1"
                         : "=v"(a[kk])
                         : "v"(hp + (size_t)kk * 2048) : "memory");
        WAIT_VM16(16, a);
        #pragma unroll
        for (int kk = 0; kk < 16; ++kk) {
            short8 bn = *(const short8*)(wn + kk * 32);
            acc2 = __builtin_amdgcn_mfma_f32_16x16x32_bf16(a[kk], bn, acc2, 0, 0, 0);
        }
        WAIT_VM16(0, (a + 16));
        #pragma unroll
        for (int kk = 16; kk < 32; ++kk) {
            short8 bn = *(const short8*)(wn + kk * 32);
            acc2 = __builtin_amdgcn_mfma_f32_16x16x32_bf16(a[kk], bn, acc2, 0, 0, 0);
        }
        pTile[(b0 + 0) * 16 + ln] = f2b(acc2[0] + bnf);
        pTile[(b0 + 1) * 16 + ln] = f2b(acc2[1] + bnf);
        pTile[(b0 + 2) * 16 + ln] = f2b(acc2[2] + bnf);
        pTile[(b0 + 3) * 16 + ln] = f2b(acc2[3] + bnf);
        __syncthreads();
        if (tid < 128) {
            short8 pv = *(const short8*)&pTile[tid * 8];
            asm volatile("global_store_dwordx4 %0, %1, off sc1"
                         :: "v"(preB + (size_t)(TT - 1) * 65536 + (size_t)bx * 1024 + tid * 8),
                            "v"(pv) : "memory");
        }
        asm volatile("s_waitcnt vmcnt(0)" ::: "memory");
        __syncthreads();
        if (tid == 0) {
            int tv = TT + 1;   // releases layer-1 t=511
            asm volatile("global_store_dword %0, %1, off sc1"
                         :: "v"(&flagsSelf[bx * 4]), "v"(tv) : "memory");
        }
    }
}

// ---------------------------------------------------------------------------
// fc: out[b] = sigmoid(dot(h2[T-1][b], Wfc) + bfc) -- h2 ring slab (TT-1)&1
// ---------------------------------------------------------------------------
__global__ __launch_bounds__(1024)
void fc_kernel(const unsigned short* __restrict__ h,
               const void* __restrict__ Wfc,
               const void* __restrict__ bfc,
               float* __restrict__ out,
               const int* __restrict__ ctl)
{
    const int mode = ctl[0];
    const int tid = threadIdx.x;
    const int b = tid >> 4, sub = tid & 15;
    const unsigned short* hr = h + (size_t)((TT - 1) & 1) * 65536 + b * 16 + sub;
    float s = 0.f;
    for (int j = 0; j < 64; ++j) {          // k = j*16 + sub
        float w = mode ? ((const float*)Wfc)[j * 16 + sub]
                       : b2f(((const unsigned short*)Wfc)[j * 16 + sub]);
        s += b2f(hr[(size_t)j * 1024]) * w;
    }
    for (int off = 8; off; off >>= 1)
        s += __shfl_down(s, off, 16);
    if (sub == 0) {
        float bv = mode ? ((const float*)bfc)[0]
                        : b2f(((const unsigned short*)bfc)[0]);
        out[b] = 1.f / (1.f + expf(-(s + bv)));
    }
}

// ---------------------------------------------------------------------------
extern "C" void kernel_launch(void* const* d_in, const int* in_sizes, int n_in,
                              void* d_out, int out_size, void* d_ws, size_t ws_size,
                              hipStream_t stream)
{
    const int*  x    = (const int*)d_in[0];
    const void* emb  = d_in[1];
    const void* Wih0 = d_in[2];
    const void* Whh0 = d_in[3];
    const void* bih0 = d_in[4];
    const void* bhh0 = d_in[5];
    const void* Wih1 = d_in[6];
    const void* Whh1 = d_in[7];
    const void* bih1 = d_in[8];
    const void* bhh1 = d_in[9];
    const void* Wfc  = d_in[10];
    const void* bfc  = d_in[11];
    float* out = (float*)d_out;

    char* ws = (char*)d_ws;
    int*            ctl  = (int*)ws;                              // 4 KiB
    unsigned short* pre  = (unsigned short*)(ws + 4096);          // 64 MiB
    unsigned short* h1   = (unsigned short*)(ws + 4096 + (size_t)67108864); // 256 KiB ring
    unsigned short* h2   = h1 + 2 * 65536;                        // 256 KiB ring

    // dtype detect + flag zeroing
    detect_kernel<<<dim3(1), dim3(64), 0, stream>>>(Whh0, ctl);
    // layer 0 input projection (one WG per t; emb staged once per WG)
    proj_kernel<<<dim3(512), dim3(256), 0, stream>>>(
        x, emb, Wih0, bih0, pre, ctl);
    // both recurrences, software-pipelined (layer 1 trails layer 0 by 2 steps)
    scan2_kernel<<<dim3(128), dim3(256), 0, stream>>>(
        pre, h1, h2, Whh0, bhh0, Wih1, bih1, Whh1, bhh1, ctl);
    // final FC + sigmoid
    fc_kernel<<<dim3(1), dim3(1024), 0, stream>>>(h2, Wfc, bfc, out, ctl);
}

// Round 18
// 2404.129 us; speedup vs baseline: 1.7755x; 1.1646x over previous
//
#include <hip/hip_runtime.h>
#include <hip/hip_bf16.h>

#define VOCAB 50000
#define EMB   300
#define HID   1024
#define TT    512
#define BB    64

// Block layout for pre: [t][kb=64][row=64][c=16] bf16; per-t slab = 65536 shorts.
// h1/h2 are 2-slab rings (slab = t&1); the per-step all-to-all flag barrier
// guarantees ring-2 reuse safety.
//
// Pipelined scan: 128 WGs. WGs 0..63 = layer 0 (FUSE: also emits
// pre1[t-1] = h1[t-1]*W_ih1^T + b_ih1, via LDS tile -> full-line sc1 stores,
// drained before flagA[bx]=t+1). WGs 64..127 = layer 1, step t gated only on
// flagsA[bx] >= t+2. A never waits on B -> no deadlock; B trails ~2 steps.
//
// Flags: 64B stride (one LLC line per flag) -> a WG's flag store no longer
// contends with 3 other WGs' stores + the poll read storm on the same line.
// Poll loops use s_sleep backoff (poll latency ~500cyc anyway) to cut LLC
// read pressure on the flag lines, speeding store visibility.
//
// detect is inlined per-WG (each kernel derives mode from its own weight
// buffer); proj WG 0 zeroes the flag region -> one fewer kernel launch.
//
// NOTE: asm "=v" load results must NEVER be live across a variable-trip loop
// and keep short straight-line ranges (allocator may spill them before the
// data lands -> garbage).

typedef __attribute__((ext_vector_type(8))) short short8;
typedef __attribute__((ext_vector_type(4))) float floatx4;

__device__ inline float b2f(unsigned int u) {
    union { unsigned int i; float f; } v; v.i = u << 16; return v.f;
}
__device__ inline unsigned short f2b(float f) {
    __hip_bfloat16 h = __float2bfloat16(f);
    return *reinterpret_cast<unsigned short*>(&h);
}

// Wait until only N of the outstanding vector loads remain, binding the first
// 16 fragments "+v" so the compiler cannot consume them earlier.
#define WAIT_VM16(N, A) asm volatile("s_waitcnt vmcnt(" #N ")"              \
    : "+v"((A)[0]), "+v"((A)[1]), "+v"((A)[2]), "+v"((A)[3]),               \
      "+v"((A)[4]), "+v"((A)[5]), "+v"((A)[6]), "+v"((A)[7]),               \
      "+v"((A)[8]), "+v"((A)[9]), "+v"((A)[10]), "+v"((A)[11]),             \
      "+v"((A)[12]), "+v"((A)[13]), "+v"((A)[14]), "+v"((A)[15])            \
    :: "memory")

// Per-wave mode probe: 1024 stride-2 bf16-interpreted samples across the
// first 256 threads; partials reduced via LDS. W must have >= 2048 shorts.
// (bf16 weights ~U(-1/32,1/32) -> in range; fp32 low-halves -> mostly junk.)
__device__ inline int detect_mode256(const void* W, int tid, int* modeSh)
{
    const unsigned short* p = (const unsigned short*)W;
    int bad = 0;
    for (int i = tid; i < 1024; i += 256) {
        float v = b2f(p[2 * i]);
        if (!(v > -0.5f && v < 0.5f)) bad++;
    }
    for (int off = 32; off; off >>= 1) bad += __shfl_down(bad, off);
    if ((tid & 63) == 0) modeSh[tid >> 6] = bad;
    return 0;  // caller must __syncthreads() then sum modeSh[0..3]
}

// ---------------------------------------------------------------------------
// proj: pre0[t*64+b][n] = bf16( emb[x[b][t]]·W_ih0^T + b_ih0 ), block layout.
// One WG per t: emb rows staged once, col-blocks looped. WG 0 zeroes flags.
// ---------------------------------------------------------------------------
__global__ __launch_bounds__(256)
void proj_kernel(const int*  __restrict__ xidx,
                 const void* __restrict__ emb,
                 const void* __restrict__ W,
                 const void* __restrict__ bias,
                 unsigned short* __restrict__ C,    // block layout bf16
                 int* __restrict__ ctl)
{
    const int t   = blockIdx.x;
    const int tid = threadIdx.x;
    __shared__ unsigned short eT[64 * 328];          // 41984 B
    __shared__ unsigned short Wl[16 * 328];          // 10496 B
    __shared__ __align__(16) unsigned short oT[1024];// 2 KB
    __shared__ int xqL[64];
    __shared__ int modeSh[4];

    if (t == 0) {   // zero both flag regions (64 flags x 16 ints x 2 sets)
        for (int i = 64 + tid; i < 64 + 2048; i += 256) ctl[i] = 0;
    }
    if (tid < 64) xqL[tid] = xidx[tid * TT + t];
    for (int i = tid; i < 64 * 28; i += 256) {       // zero eT pad
        int b = i / 28, c = 300 + i % 28;
        eT[b * 328 + c] = 0;
    }
    for (int i = tid; i < 16 * 28; i += 256) {       // zero Wl pad (stays 0)
        int nl = i / 28, c = 300 + i % 28;
        Wl[nl * 328 + c] = 0;
    }
    detect_mode256(W, tid, modeSh);
    __syncthreads();
    const int mode = (modeSh[0] + modeSh[1] + modeSh[2] + modeSh[3]) > 16;

    // stage 64 emb rows as bf16 (once)
    if (mode) {
        for (int i = tid; i < 64 * 75; i += 256) {   // 75 float4 per row
            int b = i / 75, seg = i % 75;
            const float* src = (const float*)emb
                             + (size_t)xqL[b] * EMB + seg * 4;
            float4 f = *(const float4*)src;
            unsigned short* d = &eT[b * 328 + seg * 4];
            d[0] = f2b(f.x); d[1] = f2b(f.y); d[2] = f2b(f.z); d[3] = f2b(f.w);
        }
    } else {
        for (int i = tid; i < 64 * 75; i += 256) {   // 75 uint2 per row
            int b = i / 75, seg = i % 75;
            const unsigned short* src = (const unsigned short*)emb
                                      + (size_t)xqL[b] * EMB + seg * 4;
            *(uint2*)&eT[b * 328 + seg * 4] = *(const uint2*)src;
        }
    }

    const int wave = tid >> 6, lane = tid & 63;
    const int quad = lane >> 4, ln = lane & 15;

    for (int nb = 0; nb < 64; ++nb) {
        __syncthreads();   // Wl/oT safe to overwrite (prev readers done)
        if (mode) {
            const float* Wf = (const float*)W;
            for (int i = tid; i < 16 * 75; i += 256) {
                int nl = i / 75, seg = i % 75;
                float4 f = *(const float4*)(Wf + (size_t)(nb * 16 + nl) * EMB + seg * 4);
                unsigned short* d = &Wl[nl * 328 + seg * 4];
                d[0] = f2b(f.x); d[1] = f2b(f.y); d[2] = f2b(f.z); d[3] = f2b(f.w);
            }
        } else {
            const unsigned short* Wb = (const unsigned short*)W;
            for (int i = tid; i < 16 * 75; i += 256) {
                int nl = i / 75, seg = i % 75;
                *(uint2*)&Wl[nl * 328 + seg * 4] =
                    *(const uint2*)(Wb + (size_t)(nb * 16 + nl) * EMB + seg * 4);
            }
        }
        __syncthreads();

        floatx4 acc = {0.f, 0.f, 0.f, 0.f};
        #pragma unroll
        for (int kk = 0; kk < 10; ++kk) {
            int k = kk * 32 + quad * 8;
            short8 a = *(const short8*)&eT[(wave * 16 + ln) * 328 + k];
            short8 b = *(const short8*)&Wl[ln * 328 + k];
            acc = __builtin_amdgcn_mfma_f32_16x16x32_bf16(a, b, acc, 0, 0, 0);
        }
        const int col = nb * 16 + ln;
        const float bvf = mode ? ((const float*)bias)[col]
                               : b2f(((const unsigned short*)bias)[col]);
        oT[(wave * 16 + quad * 4 + 0) * 16 + ln] = f2b(acc[0] + bvf);
        oT[(wave * 16 + quad * 4 + 1) * 16 + ln] = f2b(acc[1] + bvf);
        oT[(wave * 16 + quad * 4 + 2) * 16 + ln] = f2b(acc[2] + bvf);
        oT[(wave * 16 + quad * 4 + 3) * 16 + ln] = f2b(acc[3] + bvf);
        __syncthreads();
        if (tid < 128) {   // 2 KB contiguous -> 32 full 64B lines
            short8 hv = *(const short8*)&oT[tid * 8];
            *(short8*)(C + ((size_t)t * 64 + nb) * 1024 + tid * 8) = hv;
        }
    }
}

// ---------------------------------------------------------------------------
// scan2: both recurrences pipelined. 128 persistent WGs x 256 thr.
//   WG 0..63   (L=0): h1[t]=tanh(pre0[t]+h1[t-1]Whh0^T+bhh0), FUSE pre1[t-1].
//   WG 64..127 (L=1): h2[t]=tanh(pre1[t]+h2[t-1]Whh1^T+bhh1), gated on flagsA.
// ---------------------------------------------------------------------------
__global__ __launch_bounds__(256)
void scan2_kernel(unsigned short* __restrict__ preB,   // block layout bf16
                  unsigned short* __restrict__ h1B,    // 2-slab ring
                  unsigned short* __restrict__ h2B,    // 2-slab ring
                  const void* __restrict__ Whh0, const void* __restrict__ bhh0,
                  const void* __restrict__ Wih1, const void* __restrict__ bih1,
                  const void* __restrict__ Whh1, const void* __restrict__ bhh1,
                  int* __restrict__ ctl)
{
    const int gbx  = blockIdx.x;
    const int L    = gbx >> 6;           // 0: layer0(+fuse), 1: layer1
    const int bx   = gbx & 63;
    const int n0   = bx * 16;
    int* flagsA    = ctl + 64;                  // 64 flags, stride 16 ints
    int* flagsSelf = ctl + (L ? 64 + 1024 : 64);
    unsigned short* hB = L ? h2B : h1B;
    const void* Whh  = L ? Whh1 : Whh0;
    const void* bhhv = L ? bhh1 : bhh0;

    __shared__ unsigned short Wl[16 * 1032];
    __shared__ unsigned short Wn[16 * 1032];
    __shared__ __align__(16) unsigned short hTile[1024];
    __shared__ __align__(16) unsigned short pTile[1024];
    __shared__ int modeSh[4];
    const int tid = threadIdx.x;

    detect_mode256(Whh, tid, modeSh);
    __syncthreads();
    const int mode = (modeSh[0] + modeSh[1] + modeSh[2] + modeSh[3]) > 16;

    if (mode) {
        const float* Wf = (const float*)Whh;
        for (int i = tid; i < 16 * 256; i += 256) {
            int nl = i >> 8, c = i & 255;
            float4 f = *(const float4*)(Wf + ((size_t)(n0 + nl) << 10) + c * 4);
            unsigned short* d = &Wl[nl * 1032 + c * 4];
            d[0] = f2b(f.x); d[1] = f2b(f.y); d[2] = f2b(f.z); d[3] = f2b(f.w);
        }
        if (L == 0) {
            const float* Wg = (const float*)Wih1;
            for (int i = tid; i < 16 * 256; i += 256) {
                int nl = i >> 8, c = i & 255;
                float4 f = *(const float4*)(Wg + ((size_t)(n0 + nl) << 10) + c * 4);
                unsigned short* d = &Wn[nl * 1032 + c * 4];
                d[0] = f2b(f.x); d[1] = f2b(f.y); d[2] = f2b(f.z); d[3] = f2b(f.w);
            }
        }
    } else {
        const unsigned short* Wb = (const unsigned short*)Whh;
        for (int i = tid; i < 16 * 128; i += 256) {
            int nl = i >> 7, c = i & 127;
            *(short8*)&Wl[nl * 1032 + c * 8] =
                *(const short8*)(Wb + ((size_t)(n0 + nl) << 10) + c * 8);
        }
        if (L == 0) {
            const unsigned short* Wg = (const unsigned short*)Wih1;
            for (int i = tid; i < 16 * 128; i += 256) {
                int nl = i >> 7, c = i & 127;
                *(short8*)&Wn[nl * 1032 + c * 8] =
                    *(const short8*)(Wg + ((size_t)(n0 + nl) << 10) + c * 8);
            }
        }
    }
    __syncthreads();

    const int wave = tid >> 6, lane = tid & 63;
    const int quad = lane >> 4, ln = lane & 15;
    const int brow = wave * 16 + ln;
    const int ncol = n0 + ln;
    const float bvf = mode ? ((const float*)bhhv)[ncol]
                           : b2f(((const unsigned short*)bhhv)[ncol]);
    const float bnf = (L == 0)
        ? (mode ? ((const float*)bih1)[ncol]
                : b2f(((const unsigned short*)bih1)[ncol]))
        : 0.f;
    const int b0 = wave * 16 + quad * 4;
    const unsigned short* wl = &Wl[ln * 1032 + quad * 8];
    const unsigned short* wn = &Wn[ln * 1032 + quad * 8];
    // per-lane base offset within an h slab: k = kk*32 + quad*8
    const int hoff = (quad >> 1) * 1024 + brow * 16 + (quad & 1) * 8;

    for (int t = 0; t < TT; ++t) {
        const unsigned short* pp = preB + (size_t)t * 65536 + (size_t)bx * 1024
                                        + (size_t)b0 * 16 + ln;
        unsigned int pr0, pr1, pr2, pr3;
        floatx4 acc  = {0.f, 0.f, 0.f, 0.f};
        floatx4 acc2 = {0.f, 0.f, 0.f, 0.f};

        if (L == 0) {
            // pre0[t]: written by proj (previous kernel) -> plain loads fine.
            pr0 = pp[0]; pr1 = pp[16]; pr2 = pp[32]; pr3 = pp[48];
            if (t > 0) {
                short8 a[32];
                const unsigned short* hp = hB + (size_t)((t - 1) & 1) * 65536 + hoff;
                #pragma unroll
                for (int kk = 0; kk < 32; ++kk)
                    asm volatile("global_load_dwordx4 %0, %1, off sc1"
                                 : "=v"(a[kk])
                                 : "v"(hp + (size_t)kk * 2048) : "memory");
                WAIT_VM16(16, a);   // a[0..15] done
                #pragma unroll
                for (int kk = 0; kk < 16; ++kk) {
                    short8 b  = *(const short8*)(wl + kk * 32);
                    short8 bn = *(const short8*)(wn + kk * 32);
                    acc  = __builtin_amdgcn_mfma_f32_16x16x32_bf16(a[kk], b,  acc,  0, 0, 0);
                    acc2 = __builtin_amdgcn_mfma_f32_16x16x32_bf16(a[kk], bn, acc2, 0, 0, 0);
                }
                WAIT_VM16(0, (a + 16));
                #pragma unroll
                for (int kk = 16; kk < 32; ++kk) {
                    short8 b  = *(const short8*)(wl + kk * 32);
                    short8 bn = *(const short8*)(wn + kk * 32);
                    acc  = __builtin_amdgcn_mfma_f32_16x16x32_bf16(a[kk], b,  acc,  0, 0, 0);
                    acc2 = __builtin_amdgcn_mfma_f32_16x16x32_bf16(a[kk], bn, acc2, 0, 0, 0);
                }
            }
        } else {
            // producer wait FIRST: no asm-load results may be live across a
            // variable-trip loop (spill-before-arrival hazard).
            {
                const int* fp = &flagsA[bx * 16];
                for (;;) {
                    int v;
                    asm volatile("global_load_dword %0, %1, off sc1\n\t"
                                 "s_waitcnt vmcnt(0)"
                                 : "=v"(v) : "v"(fp) : "memory");
                    if (v >= t + 2) break;
                    asm volatile("s_sleep 2");
                }
            }
            if (t > 0) {
                short8 a[32];
                const unsigned short* hp = hB + (size_t)((t - 1) & 1) * 65536 + hoff;
                #pragma unroll
                for (int kk = 0; kk < 32; ++kk)
                    asm volatile("global_load_dwordx4 %0, %1, off sc1"
                                 : "=v"(a[kk])
                                 : "v"(hp + (size_t)kk * 2048) : "memory");
                WAIT_VM16(16, a);    // a[0..15] done (16 of 32 remain)
                #pragma unroll
                for (int kk = 0; kk < 16; ++kk) {
                    short8 b = *(const short8*)(wl + kk * 32);
                    acc = __builtin_amdgcn_mfma_f32_16x16x32_bf16(a[kk], b, acc, 0, 0, 0);
                }
                // pre1[t] (sc1: written by layer-0 peer on another XCD).
                // Issued after a[16..31]; vmcnt counts in issue order, so
                // vmcnt(4) below completes all 16 older a-loads first.
                asm volatile("global_load_ushort %0, %1, off sc1"
                             : "=v"(pr0) : "v"(pp) : "memory");
                asm volatile("global_load_ushort %0, %1, off offset:32 sc1"
                             : "=v"(pr1) : "v"(pp) : "memory");
                asm volatile("global_load_ushort %0, %1, off offset:64 sc1"
                             : "=v"(pr2) : "v"(pp) : "memory");
                asm volatile("global_load_ushort %0, %1, off offset:96 sc1"
                             : "=v"(pr3) : "v"(pp) : "memory");
                WAIT_VM16(4, (a + 16));   // a[16..31] done; pr* still in flight
                #pragma unroll
                for (int kk = 16; kk < 32; ++kk) {
                    short8 b = *(const short8*)(wl + kk * 32);
                    acc = __builtin_amdgcn_mfma_f32_16x16x32_bf16(a[kk], b, acc, 0, 0, 0);
                }
            } else {
                asm volatile("global_load_ushort %0, %1, off sc1"
                             : "=v"(pr0) : "v"(pp) : "memory");
                asm volatile("global_load_ushort %0, %1, off offset:32 sc1"
                             : "=v"(pr1) : "v"(pp) : "memory");
                asm volatile("global_load_ushort %0, %1, off offset:64 sc1"
                             : "=v"(pr2) : "v"(pp) : "memory");
                asm volatile("global_load_ushort %0, %1, off offset:96 sc1"
                             : "=v"(pr3) : "v"(pp) : "memory");
            }
            // bind pr* at a real vmcnt(0), immediately before use
            asm volatile("s_waitcnt vmcnt(0)"
                         : "+v"(pr0), "+v"(pr1), "+v"(pr2), "+v"(pr3) :: "memory");
        }

        hTile[(b0 + 0) * 16 + ln] = f2b(tanhf(acc[0] + b2f(pr0) + bvf));
        hTile[(b0 + 1) * 16 + ln] = f2b(tanhf(acc[1] + b2f(pr1) + bvf));
        hTile[(b0 + 2) * 16 + ln] = f2b(tanhf(acc[2] + b2f(pr2) + bvf));
        hTile[(b0 + 3) * 16 + ln] = f2b(tanhf(acc[3] + b2f(pr3) + bvf));
        if (L == 0 && t > 0) {
            pTile[(b0 + 0) * 16 + ln] = f2b(acc2[0] + bnf);
            pTile[(b0 + 1) * 16 + ln] = f2b(acc2[1] + bnf);
            pTile[(b0 + 2) * 16 + ln] = f2b(acc2[2] + bnf);
            pTile[(b0 + 3) * 16 + ln] = f2b(acc2[3] + bnf);
        }
        __syncthreads();
        if (tid < 128) {   // 2 KB contiguous -> 32 full 64B lines each
            short8 hv = *(const short8*)&hTile[tid * 8];
            asm volatile("global_store_dwordx4 %0, %1, off sc1"
                         :: "v"(hB + (size_t)(t & 1) * 65536 + (size_t)bx * 1024 + tid * 8),
                            "v"(hv) : "memory");
            if (L == 0 && t > 0) {
                short8 pv = *(const short8*)&pTile[tid * 8];
                asm volatile("global_store_dwordx4 %0, %1, off sc1"
                             :: "v"(preB + (size_t)(t - 1) * 65536 + (size_t)bx * 1024 + tid * 8),
                                "v"(pv) : "memory");
            }
        }
        if (t < TT - 1) {
            asm volatile("s_waitcnt vmcnt(0)" ::: "memory");
            __syncthreads();
            if (tid == 0) {
                int tv = t + 1;
                asm volatile("global_store_dword %0, %1, off sc1"
                             :: "v"(&flagsSelf[bx * 16]), "v"(tv) : "memory");
            }
            if (tid < 64) {
                const int* fp = &flagsSelf[tid * 16];
                for (;;) {
                    int v;
                    asm volatile("global_load_dword %0, %1, off sc1\n\t"
                                 "s_waitcnt vmcnt(0)"
                                 : "=v"(v) : "v"(fp) : "memory");
                    if (!__any(v < t + 1)) break;
                    asm volatile("s_sleep 1");
                }
            }
            __syncthreads();
        }
    }

    if (L == 0) {   // tail: pre1[511] needs full h1[511] -> one barrier round
        asm volatile("s_waitcnt vmcnt(0)" ::: "memory");
        __syncthreads();
        if (tid == 0) {
            int tv = TT;   // also releases layer-1 t=510 (needs pre1[510])
            asm volatile("global_store_dword %0, %1, off sc1"
                         :: "v"(&flagsSelf[bx * 16]), "v"(tv) : "memory");
        }
        if (tid < 64) {
            const int* fp = &flagsSelf[tid * 16];
            for (;;) {
                int v;
                asm volatile("global_load_dword %0, %1, off sc1\n\t"
                             "s_waitcnt vmcnt(0)"
                             : "=v"(v) : "v"(fp) : "memory");
                if (!__any(v < TT)) break;
                asm volatile("s_sleep 1");
            }
        }
        __syncthreads();

        const unsigned short* hp = hB + (size_t)((TT - 1) & 1) * 65536 + hoff;
        short8 a[32];
        floatx4 acc2 = {0.f, 0.f, 0.f, 0.f};
        #pragma unroll
        for (int kk = 0; kk < 32; ++kk)
            asm volatile("global_load_dwordx4 %0, %1, off sc1"
                         : "=v"(a[kk])
                         : "v"(hp + (size_t)kk * 2048) : "memory");
        WAIT_VM16(16, a);
        #pragma unroll
        for (int kk = 0; kk < 16; ++kk) {
            short8 bn = *(const short8*)(wn + kk * 32);
            acc2 = __builtin_amdgcn_mfma_f32_16x16x32_bf16(a[kk], bn, acc2, 0, 0, 0);
        }
        WAIT_VM16(0, (a + 16));
        #pragma unroll
        for (int kk = 16; kk < 32; ++kk) {
            short8 bn = *(const short8*)(wn + kk * 32);
            acc2 = __builtin_amdgcn_mfma_f32_16x16x32_bf16(a[kk], bn, acc2, 0, 0, 0);
        }
        pTile[(b0 + 0) * 16 + ln] = f2b(acc2[0] + bnf);
        pTile[(b0 + 1) * 16 + ln] = f2b(acc2[1] + bnf);
        pTile[(b0 + 2) * 16 + ln] = f2b(acc2[2] + bnf);
        pTile[(b0 + 3) * 16 + ln] = f2b(acc2[3] + bnf);
        __syncthreads();
        if (tid < 128) {
            short8 pv = *(const short8*)&pTile[tid * 8];
            asm volatile("global_store_dwordx4 %0, %1, off sc1"
                         :: "v"(preB + (size_t)(TT - 1) * 65536 + (size_t)bx * 1024 + tid * 8),
                            "v"(pv) : "memory");
        }
        asm volatile("s_waitcnt vmcnt(0)" ::: "memory");
        __syncthreads();
        if (tid == 0) {
            int tv = TT + 1;   // releases layer-1 t=511
            asm volatile("global_store_dword %0, %1, off sc1"
                         :: "v"(&flagsSelf[bx * 16]), "v"(tv) : "memory");
        }
    }
}

// ---------------------------------------------------------------------------
// fc: out[b] = sigmoid(dot(h2[T-1][b], Wfc) + bfc) -- h2 ring slab (TT-1)&1
// Mode detected from WhhD (Whh1: >=2048 shorts in either dtype).
// ---------------------------------------------------------------------------
__global__ __launch_bounds__(1024)
void fc_kernel(const unsigned short* __restrict__ h,
               const void* __restrict__ Wfc,
               const void* __restrict__ bfc,
               const void* __restrict__ WhhD,
               float* __restrict__ out)
{
    const int tid = threadIdx.x;
    __shared__ int modeSh[16];
    {
        const unsigned short* p = (const unsigned short*)WhhD;
        int bad = 0;
        if (tid < 1024) {
            float v = b2f(p[2 * tid]);
            if (!(v > -0.5f && v < 0.5f)) bad++;
        }
        for (int off = 32; off; off >>= 1) bad += __shfl_down(bad, off);
        if ((tid & 63) == 0) modeSh[tid >> 6] = bad;
    }
    __syncthreads();
    int modeSum = 0;
    for (int w = 0; w < 16; ++w) modeSum += modeSh[w];
    const int mode = modeSum > 16;

    const int b = tid >> 4, sub = tid & 15;
    const unsigned short* hr = h + (size_t)((TT - 1) & 1) * 65536 + b * 16 + sub;
    float s = 0.f;
    for (int j = 0; j < 64; ++j) {          // k = j*16 + sub
        float w = mode ? ((const float*)Wfc)[j * 16 + sub]
                       : b2f(((const unsigned short*)Wfc)[j * 16 + sub]);
        s += b2f(hr[(size_t)j * 1024]) * w;
    }
    for (int off = 8; off; off >>= 1)
        s += __shfl_down(s, off, 16);
    if (sub == 0) {
        float bv = mode ? ((const float*)bfc)[0]
                        : b2f(((const unsigned short*)bfc)[0]);
        out[b] = 1.f / (1.f + expf(-(s + bv)));
    }
}

// ---------------------------------------------------------------------------
extern "C" void kernel_launch(void* const* d_in, const int* in_sizes, int n_in,
                              void* d_out, int out_size, void* d_ws, size_t ws_size,
                              hipStream_t stream)
{
    const int*  x    = (const int*)d_in[0];
    const void* emb  = d_in[1];
    const void* Wih0 = d_in[2];
    const void* Whh0 = d_in[3];
    const void* bih0 = d_in[4];
    const void* bhh0 = d_in[5];
    const void* Wih1 = d_in[6];
    const void* Whh1 = d_in[7];
    const void* bih1 = d_in[8];
    const void* bhh1 = d_in[9];
    const void* Wfc  = d_in[10];
    const void* bfc  = d_in[11];
    float* out = (float*)d_out;

    char* ws = (char*)d_ws;
    int*            ctl  = (int*)ws;                              // 16 KiB (flags @64B stride)
    unsigned short* pre  = (unsigned short*)(ws + 16384);         // 64 MiB
    unsigned short* h1   = (unsigned short*)(ws + 16384 + (size_t)67108864); // 256 KiB ring
    unsigned short* h2   = h1 + 2 * 65536;                        // 256 KiB ring

    // layer 0 input projection (one WG per t; emb staged once; WG0 zeroes flags)
    proj_kernel<<<dim3(512), dim3(256), 0, stream>>>(
        x, emb, Wih0, bih0, pre, ctl);
    // both recurrences, software-pipelined (layer 1 trails layer 0 by 2 steps)
    scan2_kernel<<<dim3(128), dim3(256), 0, stream>>>(
        pre, h1, h2, Whh0, bhh0, Wih1, bih1, Whh1, bhh1, ctl);
    // final FC + sigmoid
    fc_kernel<<<dim3(1), dim3(1024), 0, stream>>>(h2, Wfc, bfc, Whh1, out);
}